// Round 20
// baseline (189.520 us; speedup 1.0000x reference)
//
#include <hip/hip_runtime.h>

#define HID 50
#define TSTEPS 512

typedef _Float16 h2v __attribute__((ext_vector_type(2)));

__device__ __forceinline__ float fdot2(h2v a, h2v b, float c) {
#if __has_builtin(__builtin_amdgcn_fdot2)
    return __builtin_amdgcn_fdot2(a, b, c, false);
#else
    asm("v_dot2_f32_f16 %0, %1, %2, %0" : "+v"(c) : "v"(a), "v"(b));
    return c;
#endif
}
__device__ __forceinline__ h2v bits_to_h2(unsigned u) {
    h2v r; __builtin_memcpy(&r, &u, sizeof(r)); return r;
}

// Row-split occupancy doubler. R16/R19 established: the ~265cy per-step chain
// (LDS h-table round trip + dot2 + tanh) cannot be hidden within a wave, and
// 1 batch/wave caps the machine at 2 waves/SIMD (2048 batches = 2048 waves)
// with measured ZERO cross-wave overlap (step-pair = 2x chain).
// Fix: workgroup = 2 waves sharing ONE batch; wave w owns rows w*25..w*25+24
// (25 active lanes). 2048 wgs x 2 waves = 4096 waves = 4/SIMD. Per-batch
// issue stays ~170cy/step; 4 independent chains per SIMD to interleave.
// Double-buffered h table (read t&1, write t^1) -> ONE barrier per step.
// fp16 h + v_dot2_f32_f16 (R16-proven: passed, absmax 2^-7 = harness ok).
__global__ __launch_bounds__(128) __attribute__((amdgpu_waves_per_eu(4, 4)))
void rnn_fused(
    const float* __restrict__ x,      // [B, 512, 1]
    const float* __restrict__ W_ih,   // [50, 1]
    const float* __restrict__ W_hh,   // [50, 50]
    const float* __restrict__ b_ih,   // [50]
    const float* __restrict__ b_hh,   // [50]
    const float* __restrict__ W_fc,   // [1, 50]
    const float* __restrict__ b_fc,   // [1]
    float* __restrict__ out)          // [B, 1]
{
    const int tid = threadIdx.x;      // 0..127
    const int w   = tid >> 6;         // wave: 0 -> rows 0..24, 1 -> rows 25..49
    const int l   = tid & 63;
    const int b   = blockIdx.x;
    const bool writer = (l < 25);
    const int jrow = w * 25 + (writer ? l : 0);   // idle lanes dup row w*25
    const float SC = 2.8853900817779268f;         // 2*log2(e)

    __shared__ __align__(16) _Float16 hht[2][64]; // double-buffered h table
    __shared__ __align__(16) float xbuf[64];
    __shared__ float psum[2];

    h2v w2[25];
#pragma unroll
    for (int m = 0; m < 25; ++m) {
        h2v t;
        t.x = (_Float16)(W_hh[jrow * HID + 2 * m]     * SC);
        t.y = (_Float16)(W_hh[jrow * HID + 2 * m + 1] * SC);
        w2[m] = t;
    }
    const float wih  = W_ih[jrow] * SC;
    const float btot = (b_ih[jrow] + b_hh[jrow]) * SC;
    const float wfc  = writer ? W_fc[jrow] : 0.0f;
    const float bfc  = b_fc[0];

    const float* xb = x + (size_t)b * TSTEPS;
    float xv = 0.0f;
    if (w == 0) xv = xb[l];           // wave0 stages x
    float hn = 0.0f;

    // init both buffers (slots 50..63 stay 0 forever -> quad tails inert)
    if (tid < 64) {
        hht[0][tid] = (_Float16)0.0f;
        hht[1][tid] = (_Float16)0.0f;
    }
    __syncthreads();

    for (int c = 0; c < TSTEPS / 64; ++c) {
        if (w == 0) xbuf[l] = xv;     // previous step's barrier protects old reads
        float xvn = 0.0f;
        if (w == 0 && c + 1 < TSTEPS / 64) xvn = xb[(c + 1) * 64 + l];
        __syncthreads();

        for (int g = 0; g < 8; ++g) {
#pragma unroll
            for (int ii = 0; ii < 8; ++ii) {
                const int p = ii & 1;               // t = c*64+g*8+ii -> parity ii&1
                const float xt = xbuf[g * 8 + ii];  // uniform addr -> broadcast
                const uint4* h8 = reinterpret_cast<const uint4*>(&hht[p][0]);

                float a0 = btot, a1 = 0.f, a2 = 0.f, a3 = 0.f;
#pragma unroll
                for (int q = 0; q < 7; ++q) {
                    const uint4 u = h8[q];          // ds_read_b128 broadcast
                    const int m = 4 * q;
                    a0 = fdot2(bits_to_h2(u.x), w2[m], a0);
                    if (m + 1 < 25) a1 = fdot2(bits_to_h2(u.y), w2[m + 1], a1);
                    if (m + 2 < 25) a2 = fdot2(bits_to_h2(u.z), w2[m + 2], a2);
                    if (m + 3 < 25) a3 = fdot2(bits_to_h2(u.w), w2[m + 3], a3);
                }
                const float z = fmaf(xt, wih, (a0 + a1) + (a2 + a3));
                const float e = __builtin_amdgcn_exp2f(z);
                hn = fmaf(-2.0f, __builtin_amdgcn_rcpf(e + 1.0f), 1.0f);

                // write NEXT buffer (no race with this step's reads of buf p)
                if (writer) hht[p ^ 1][jrow] = (_Float16)hn;
                __syncthreads();                    // one barrier per step
            }
        }
        xv = xvn;
    }

    // epilogue: lane holds h_T[jrow] (fp32). Reduce 25 writers per wave,
    // combine the two waves via LDS.
    float pr = writer ? hn * wfc : 0.0f;
#pragma unroll
    for (int off = 32; off >= 1; off >>= 1) pr += __shfl_xor(pr, off);
    if (l == 0) psum[w] = pr;
    __syncthreads();
    if (tid == 0) out[b] = psum[0] + psum[1] + bfc;
}

extern "C" void kernel_launch(void* const* d_in, const int* in_sizes, int n_in,
                              void* d_out, int out_size, void* d_ws, size_t ws_size,
                              hipStream_t stream) {
    (void)d_ws; (void)ws_size; (void)n_in; (void)out_size;
    const float* x    = (const float*)d_in[0];
    const float* W_ih = (const float*)d_in[1];
    const float* W_hh = (const float*)d_in[2];
    const float* b_ih = (const float*)d_in[3];
    const float* b_hh = (const float*)d_in[4];
    const float* W_fc = (const float*)d_in[5];
    const float* b_fc = (const float*)d_in[6];
    float* out = (float*)d_out;

    const int B = in_sizes[0] / TSTEPS;   // 2048
    rnn_fused<<<dim3(B), dim3(128), 0, stream>>>(x, W_ih, W_hh, b_ih, b_hh,
                                                 W_fc, b_fc, out);
}

// Round 21
// 103.684 us; speedup vs baseline: 1.8279x; 1.8279x over previous
//
#include <hip/hip_runtime.h>

#define HID 50
#define TSTEPS 512

typedef _Float16 h2v __attribute__((ext_vector_type(2)));

__device__ __forceinline__ float fdot2(h2v a, h2v b, float c) {
#if __has_builtin(__builtin_amdgcn_fdot2)
    return __builtin_amdgcn_fdot2(a, b, c, false);
#else
    asm("v_dot2_f32_f16 %0, %1, %2, %0" : "+v"(c) : "v"(a), "v"(b));
    return c;
#endif
}
__device__ __forceinline__ h2v bits_to_h2(unsigned u) {
    h2v r; __builtin_memcpy(&r, &u, sizeof(r)); return r;
}

// R16 structure (best: 113us) minus its two remaining overheads:
//  1. NO barriers in the recurrence. Same-wave DS ops complete in order on
//     gfx950 (R18/R19: write->read with no barrier, validated twice, exact
//     absmax). R16's __syncthreads forced lgkmcnt(0) write-ack drain INSIDE
//     the serial chain; barrier-free, the write queues ahead of the reads
//     and all waits are counted first-use waits. sched_barrier(0) per step
//     stops cross-step schedule melt (the R7 barrier-free pathology).
//  2. Recurrence predicated to 50 lanes (if j<HID hoisted per chunk):
//     exec-masked lanes receive no LDS broadcast data -> 800B vs 1024B per
//     quad = 22% less return-network traffic (R16 measured ~85% saturated:
//     7KB/wave-step x 8 waves/CU over 256B/clk = 224 of 264 cyc).
// fp16 h + v_dot2_f32_f16 (R16-proven: passed, absmax 2^-7).
__global__ __launch_bounds__(64) __attribute__((amdgpu_waves_per_eu(2, 2)))
void rnn_fused(
    const float* __restrict__ x,      // [B, 512, 1]
    const float* __restrict__ W_ih,   // [50, 1]
    const float* __restrict__ W_hh,   // [50, 50]
    const float* __restrict__ b_ih,   // [50]
    const float* __restrict__ b_hh,   // [50]
    const float* __restrict__ W_fc,   // [1, 50]
    const float* __restrict__ b_fc,   // [1]
    float* __restrict__ out)          // [B, 1]
{
    const int b = blockIdx.x;
    const int j = threadIdx.x;        // 0..63; lanes 50..63 only stage x
    __shared__ __align__(16) _Float16 hht[64];   // h table; slots 50..63 = 0
    __shared__ __align__(16) float xbuf[64];

    const int jj = (j < HID) ? j : 0;
    const float SC = 2.8853900817779268f;   // 2*log2(e)

    h2v w2[25];
#pragma unroll
    for (int m = 0; m < 25; ++m) {
        h2v t;
        t.x = (_Float16)(W_hh[jj * HID + 2 * m]     * SC);
        t.y = (_Float16)(W_hh[jj * HID + 2 * m + 1] * SC);
        w2[m] = t;
    }
    const float wih  = W_ih[jj] * SC;
    const float btot = (b_ih[jj] + b_hh[jj]) * SC;
    const float wfc  = (j < HID) ? W_fc[jj] : 0.0f;
    const float bfc  = b_fc[0];

    const float* xb = x + (size_t)b * TSTEPS;
    float xv = xb[j];                 // 64 timesteps of x, one per lane
    float hn = 0.0f;
    hht[j] = (_Float16)0.0f;          // h0 = 0 (all 64 slots; 50..63 stay 0)
    // no barrier: same-wave in-order DS covers write->read (R18/R19-proven)

    for (int c = 0; c < TSTEPS / 64; ++c) {
        xbuf[j] = xv;                 // staged by all 64 lanes, in-order DS
        float xv_next = 0.0f;
        if (c + 1 < TSTEPS / 64) xv_next = xb[(c + 1) * 64 + j];

        if (j < HID) {                // one exec-mask toggle per 64 steps
            for (int g = 0; g < 8; ++g) {
#pragma unroll
                for (int ii = 0; ii < 8; ++ii) {
                    const int t = g * 8 + ii;

                    hht[j] = (_Float16)hn;        // write first: queues ahead
                    const float xt = xbuf[t];     // of the reads below
                    const uint4* h8 = reinterpret_cast<const uint4*>(hht);

                    float a0 = btot, a1 = 0.f, a2 = 0.f, a3 = 0.f;
#pragma unroll
                    for (int q = 0; q < 7; ++q) {
                        const uint4 u = h8[q];    // b128 bcast, counted waits
                        const int m = 4 * q;
                        a0 = fdot2(bits_to_h2(u.x), w2[m], a0);
                        if (m + 1 < 25) a1 = fdot2(bits_to_h2(u.y), w2[m + 1], a1);
                        if (m + 2 < 25) a2 = fdot2(bits_to_h2(u.z), w2[m + 2], a2);
                        if (m + 3 < 25) a3 = fdot2(bits_to_h2(u.w), w2[m + 3], a3);
                    }
                    const float z = fmaf(xt, wih, (a0 + a1) + (a2 + a3));

                    // tanh(s) = 1 - 2/(exp2(z)+1); saturates at +-inf
                    const float e = __builtin_amdgcn_exp2f(z);
                    const float r = __builtin_amdgcn_rcpf(e + 1.0f);
                    hn = fmaf(-2.0f, r, 1.0f);

                    __builtin_amdgcn_sched_barrier(0);  // pin step boundary
                }
            }
        }
        xv = xv_next;
    }

    // out[b] = sum_j h_T[j]*W_fc[j] + b_fc (lanes >= 50: hn=0, wfc=0)
    float pr = hn * wfc;
#pragma unroll
    for (int off = 32; off >= 1; off >>= 1) pr += __shfl_xor(pr, off);
    if (j == 0) out[b] = pr + bfc;
}

extern "C" void kernel_launch(void* const* d_in, const int* in_sizes, int n_in,
                              void* d_out, int out_size, void* d_ws, size_t ws_size,
                              hipStream_t stream) {
    (void)d_ws; (void)ws_size; (void)n_in; (void)out_size;
    const float* x    = (const float*)d_in[0];
    const float* W_ih = (const float*)d_in[1];
    const float* W_hh = (const float*)d_in[2];
    const float* b_ih = (const float*)d_in[3];
    const float* b_hh = (const float*)d_in[4];
    const float* W_fc = (const float*)d_in[5];
    const float* b_fc = (const float*)d_in[6];
    float* out = (float*)d_out;

    const int B = in_sizes[0] / TSTEPS;   // 2048
    rnn_fused<<<dim3(B), dim3(64), 0, stream>>>(x, W_ih, W_hh, b_ih, b_hh,
                                                W_fc, b_fc, out);
}

// Round 22
// 99.707 us; speedup vs baseline: 1.9008x; 1.0399x over previous
//
#include <hip/hip_runtime.h>

#define HID 50
#define TSTEPS 512

typedef _Float16 h2v __attribute__((ext_vector_type(2)));

__device__ __forceinline__ float fdot2(h2v a, h2v b, float c) {
#if __has_builtin(__builtin_amdgcn_fdot2)
    return __builtin_amdgcn_fdot2(a, b, c, false);
#else
    asm("v_dot2_f32_f16 %0, %1, %2, %0" : "+v"(c) : "v"(a), "v"(b));
    return c;
#endif
}
__device__ __forceinline__ h2v bits_to_h2(unsigned u) {
    h2v r; __builtin_memcpy(&r, &u, sizeof(r)); return r;
}

// R21 + s_setprio convoy breaker.
// Measured facts: R16 == R21 == 113.0us exactly (barrier removal and -22%
// broadcast traffic both neutral) -> neither drains nor LDS BW binding.
// Step wall 530cy = 330 issue (2 waves x 165) + 200 simultaneous stall:
// the two identical co-resident waves CONVOY (round-robin issue keeps them
// phase-locked; their ~150cy LDS-read stalls coincide). Perfect anti-phase
// would give wall = max(330, 264-cy chain) = 330 -> ~70us.
// Fix: memory-issue phase at prio 0, compute phase at prio 1. A computing
// wave beats the other wave's read-burst issue -> bursts (and stalls) slide
// apart -> stable anti-phase. (T5's mechanism: arbitration needs role
// diversity; the two phases provide it.)
__global__ __launch_bounds__(64) __attribute__((amdgpu_waves_per_eu(2, 2)))
void rnn_fused(
    const float* __restrict__ x,      // [B, 512, 1]
    const float* __restrict__ W_ih,   // [50, 1]
    const float* __restrict__ W_hh,   // [50, 50]
    const float* __restrict__ b_ih,   // [50]
    const float* __restrict__ b_hh,   // [50]
    const float* __restrict__ W_fc,   // [1, 50]
    const float* __restrict__ b_fc,   // [1]
    float* __restrict__ out)          // [B, 1]
{
    const int b = blockIdx.x;
    const int j = threadIdx.x;        // 0..63; lanes 50..63 only stage x
    __shared__ __align__(16) _Float16 hht[64];   // h table; slots 50..63 = 0
    __shared__ __align__(16) float xbuf[64];

    const int jj = (j < HID) ? j : 0;
    const float SC = 2.8853900817779268f;   // 2*log2(e)

    h2v w2[25];
#pragma unroll
    for (int m = 0; m < 25; ++m) {
        h2v t;
        t.x = (_Float16)(W_hh[jj * HID + 2 * m]     * SC);
        t.y = (_Float16)(W_hh[jj * HID + 2 * m + 1] * SC);
        w2[m] = t;
    }
    const float wih  = W_ih[jj] * SC;
    const float btot = (b_ih[jj] + b_hh[jj]) * SC;
    const float wfc  = (j < HID) ? W_fc[jj] : 0.0f;
    const float bfc  = b_fc[0];

    const float* xb = x + (size_t)b * TSTEPS;
    float xv = xb[j];                 // 64 timesteps of x, one per lane
    float hn = 0.0f;
    hht[j] = (_Float16)0.0f;          // h0 = 0 (slots 50..63 stay 0 forever)
    // no barrier: same-wave in-order DS covers write->read (R18/R19-proven)

    for (int c = 0; c < TSTEPS / 64; ++c) {
        xbuf[j] = xv;                 // staged by all 64 lanes, in-order DS
        float xv_next = 0.0f;
        if (c + 1 < TSTEPS / 64) xv_next = xb[(c + 1) * 64 + j];

        if (j < HID) {                // one exec-mask toggle per 64 steps
            for (int g = 0; g < 8; ++g) {
#pragma unroll
                for (int ii = 0; ii < 8; ++ii) {
                    const int t = g * 8 + ii;

                    // ---- memory-issue phase at prio 0
                    __builtin_amdgcn_s_setprio(0);
                    hht[j] = (_Float16)hn;        // write first: queues ahead
                    const float xt = xbuf[t];     // of the reads below
                    const uint4* h8 = reinterpret_cast<const uint4*>(hht);
                    uint4 u0 = h8[0], u1 = h8[1], u2 = h8[2], u3 = h8[3],
                          u4 = h8[4], u5 = h8[5], u6 = h8[6];

                    // ---- compute phase at prio 1 (prio latched across the
                    //      auto-waitcnt stall; a computing wave outprioritizes
                    //      the other wave's read burst -> anti-phase)
                    __builtin_amdgcn_s_setprio(1);
                    float a0 = btot, a1 = 0.f, a2 = 0.f, a3 = 0.f;
                    a0 = fdot2(bits_to_h2(u0.x), w2[0],  a0);
                    a1 = fdot2(bits_to_h2(u0.y), w2[1],  a1);
                    a2 = fdot2(bits_to_h2(u0.z), w2[2],  a2);
                    a3 = fdot2(bits_to_h2(u0.w), w2[3],  a3);
                    a0 = fdot2(bits_to_h2(u1.x), w2[4],  a0);
                    a1 = fdot2(bits_to_h2(u1.y), w2[5],  a1);
                    a2 = fdot2(bits_to_h2(u1.z), w2[6],  a2);
                    a3 = fdot2(bits_to_h2(u1.w), w2[7],  a3);
                    a0 = fdot2(bits_to_h2(u2.x), w2[8],  a0);
                    a1 = fdot2(bits_to_h2(u2.y), w2[9],  a1);
                    a2 = fdot2(bits_to_h2(u2.z), w2[10], a2);
                    a3 = fdot2(bits_to_h2(u2.w), w2[11], a3);
                    a0 = fdot2(bits_to_h2(u3.x), w2[12], a0);
                    a1 = fdot2(bits_to_h2(u3.y), w2[13], a1);
                    a2 = fdot2(bits_to_h2(u3.z), w2[14], a2);
                    a3 = fdot2(bits_to_h2(u3.w), w2[15], a3);
                    a0 = fdot2(bits_to_h2(u4.x), w2[16], a0);
                    a1 = fdot2(bits_to_h2(u4.y), w2[17], a1);
                    a2 = fdot2(bits_to_h2(u4.z), w2[18], a2);
                    a3 = fdot2(bits_to_h2(u4.w), w2[19], a3);
                    a0 = fdot2(bits_to_h2(u5.x), w2[20], a0);
                    a1 = fdot2(bits_to_h2(u5.y), w2[21], a1);
                    a2 = fdot2(bits_to_h2(u5.z), w2[22], a2);
                    a3 = fdot2(bits_to_h2(u5.w), w2[23], a3);
                    a0 = fdot2(bits_to_h2(u6.x), w2[24], a0);
                    const float z = fmaf(xt, wih, (a0 + a1) + (a2 + a3));

                    // tanh(s) = 1 - 2/(exp2(z)+1); saturates at +-inf
                    const float e = __builtin_amdgcn_exp2f(z);
                    const float r = __builtin_amdgcn_rcpf(e + 1.0f);
                    hn = fmaf(-2.0f, r, 1.0f);

                    __builtin_amdgcn_sched_barrier(0);  // pin step boundary
                }
            }
        }
        xv = xv_next;
    }
    __builtin_amdgcn_s_setprio(0);

    // out[b] = sum_j h_T[j]*W_fc[j] + b_fc (lanes >= 50: hn=0, wfc=0)
    float pr = hn * wfc;
#pragma unroll
    for (int off = 32; off >= 1; off >>= 1) pr += __shfl_xor(pr, off);
    if (j == 0) out[b] = pr + bfc;
}

extern "C" void kernel_launch(void* const* d_in, const int* in_sizes, int n_in,
                              void* d_out, int out_size, void* d_ws, size_t ws_size,
                              hipStream_t stream) {
    (void)d_ws; (void)ws_size; (void)n_in; (void)out_size;
    const float* x    = (const float*)d_in[0];
    const float* W_ih = (const float*)d_in[1];
    const float* W_hh = (const float*)d_in[2];
    const float* b_ih = (const float*)d_in[3];
    const float* b_hh = (const float*)d_in[4];
    const float* W_fc = (const float*)d_in[5];
    const float* b_fc = (const float*)d_in[6];
    float* out = (float*)d_out;

    const int B = in_sizes[0] / TSTEPS;   // 2048
    rnn_fused<<<dim3(B), dim3(64), 0, stream>>>(x, W_ih, W_hh, b_ih, b_hh,
                                                W_fc, b_fc, out);
}

// Round 23
// 99.660 us; speedup vs baseline: 1.9017x; 1.0005x over previous
//
#include <hip/hip_runtime.h>

#define HID 50
#define TSTEPS 512

typedef _Float16 h2v __attribute__((ext_vector_type(2)));

__device__ __forceinline__ float fdot2(h2v a, h2v b, float c) {
#if __has_builtin(__builtin_amdgcn_fdot2)
    return __builtin_amdgcn_fdot2(a, b, c, false);
#else
    asm("v_dot2_f32_f16 %0, %1, %2, %0" : "+v"(c) : "v"(a), "v"(b));
    return c;
#endif
}
__device__ __forceinline__ h2v bits_to_h2(unsigned u) {
    h2v r; __builtin_memcpy(&r, &u, sizeof(r)); return r;
}

// R22 (setprio phase-split, +4% real) + hash-staggered start.
// Accounting after R22: per-wave step 508cy; VALU issue 166cy/wave-step ->
// issue floor 332cy/step-pair (~70us @ 100% busy). Residual ~175cy = both
// waves' LDS-stall windows still overlapping (convoy). Two cycle-identical
// waves that START in phase STAY in phase (no restoring drift in steady
// state) -- so give each block a pseudo-random 0..448cy s_sleep delay before
// the recurrence. Whatever the block->SIMD pairing, hashed offsets differ by
// ~256cy in expectation -> one wave's stall slides into the other's compute.
__global__ __launch_bounds__(64) __attribute__((amdgpu_waves_per_eu(2, 2)))
void rnn_fused(
    const float* __restrict__ x,      // [B, 512, 1]
    const float* __restrict__ W_ih,   // [50, 1]
    const float* __restrict__ W_hh,   // [50, 50]
    const float* __restrict__ b_ih,   // [50]
    const float* __restrict__ b_hh,   // [50]
    const float* __restrict__ W_fc,   // [1, 50]
    const float* __restrict__ b_fc,   // [1]
    float* __restrict__ out)          // [B, 1]
{
    const int b = blockIdx.x;
    const int j = threadIdx.x;        // 0..63; lanes 50..63 only stage x
    __shared__ __align__(16) _Float16 hht[64];   // h table; slots 50..63 = 0
    __shared__ __align__(16) float xbuf[64];

    const int jj = (j < HID) ? j : 0;
    const float SC = 2.8853900817779268f;   // 2*log2(e)

    h2v w2[25];
#pragma unroll
    for (int m = 0; m < 25; ++m) {
        h2v t;
        t.x = (_Float16)(W_hh[jj * HID + 2 * m]     * SC);
        t.y = (_Float16)(W_hh[jj * HID + 2 * m + 1] * SC);
        w2[m] = t;
    }
    const float wih  = W_ih[jj] * SC;
    const float btot = (b_ih[jj] + b_hh[jj]) * SC;
    const float wfc  = (j < HID) ? W_fc[jj] : 0.0f;
    const float bfc  = b_fc[0];

    const float* xb = x + (size_t)b * TSTEPS;
    float xv = xb[j];                 // 64 timesteps of x, one per lane
    float hn = 0.0f;
    hht[j] = (_Float16)0.0f;          // h0 = 0 (slots 50..63 stay 0 forever)

    // phase stagger: 0..7 x 64cy pseudo-random delay, uniform per wave
    {
        const unsigned sd = (((unsigned)blockIdx.x) * 2654435761u) >> 29; // 0..7
        for (unsigned k = 0; k < sd; ++k) __builtin_amdgcn_s_sleep(1);
    }

    for (int c = 0; c < TSTEPS / 64; ++c) {
        xbuf[j] = xv;                 // staged by all 64 lanes, in-order DS
        float xv_next = 0.0f;
        if (c + 1 < TSTEPS / 64) xv_next = xb[(c + 1) * 64 + j];

        if (j < HID) {                // one exec-mask toggle per 64 steps
            for (int g = 0; g < 8; ++g) {
#pragma unroll
                for (int ii = 0; ii < 8; ++ii) {
                    const int t = g * 8 + ii;

                    // ---- memory-issue phase at prio 0
                    __builtin_amdgcn_s_setprio(0);
                    hht[j] = (_Float16)hn;        // write first: queues ahead
                    const float xt = xbuf[t];     // of the reads below
                    const uint4* h8 = reinterpret_cast<const uint4*>(hht);
                    uint4 u0 = h8[0], u1 = h8[1], u2 = h8[2], u3 = h8[3],
                          u4 = h8[4], u5 = h8[5], u6 = h8[6];

                    // ---- compute phase at prio 1
                    __builtin_amdgcn_s_setprio(1);
                    float a0 = btot, a1 = 0.f, a2 = 0.f, a3 = 0.f;
                    a0 = fdot2(bits_to_h2(u0.x), w2[0],  a0);
                    a1 = fdot2(bits_to_h2(u0.y), w2[1],  a1);
                    a2 = fdot2(bits_to_h2(u0.z), w2[2],  a2);
                    a3 = fdot2(bits_to_h2(u0.w), w2[3],  a3);
                    a0 = fdot2(bits_to_h2(u1.x), w2[4],  a0);
                    a1 = fdot2(bits_to_h2(u1.y), w2[5],  a1);
                    a2 = fdot2(bits_to_h2(u1.z), w2[6],  a2);
                    a3 = fdot2(bits_to_h2(u1.w), w2[7],  a3);
                    a0 = fdot2(bits_to_h2(u2.x), w2[8],  a0);
                    a1 = fdot2(bits_to_h2(u2.y), w2[9],  a1);
                    a2 = fdot2(bits_to_h2(u2.z), w2[10], a2);
                    a3 = fdot2(bits_to_h2(u2.w), w2[11], a3);
                    a0 = fdot2(bits_to_h2(u3.x), w2[12], a0);
                    a1 = fdot2(bits_to_h2(u3.y), w2[13], a1);
                    a2 = fdot2(bits_to_h2(u3.z), w2[14], a2);
                    a3 = fdot2(bits_to_h2(u3.w), w2[15], a3);
                    a0 = fdot2(bits_to_h2(u4.x), w2[16], a0);
                    a1 = fdot2(bits_to_h2(u4.y), w2[17], a1);
                    a2 = fdot2(bits_to_h2(u4.z), w2[18], a2);
                    a3 = fdot2(bits_to_h2(u4.w), w2[19], a3);
                    a0 = fdot2(bits_to_h2(u5.x), w2[20], a0);
                    a1 = fdot2(bits_to_h2(u5.y), w2[21], a1);
                    a2 = fdot2(bits_to_h2(u5.z), w2[22], a2);
                    a3 = fdot2(bits_to_h2(u5.w), w2[23], a3);
                    a0 = fdot2(bits_to_h2(u6.x), w2[24], a0);
                    const float z = fmaf(xt, wih, (a0 + a1) + (a2 + a3));

                    // tanh(s) = 1 - 2/(exp2(z)+1); saturates at +-inf
                    const float e = __builtin_amdgcn_exp2f(z);
                    const float r = __builtin_amdgcn_rcpf(e + 1.0f);
                    hn = fmaf(-2.0f, r, 1.0f);

                    __builtin_amdgcn_sched_barrier(0);  // pin step boundary
                }
            }
        }
        xv = xv_next;
    }
    __builtin_amdgcn_s_setprio(0);

    // out[b] = sum_j h_T[j]*W_fc[j] + b_fc (lanes >= 50: hn=0, wfc=0)
    float pr = hn * wfc;
#pragma unroll
    for (int off = 32; off >= 1; off >>= 1) pr += __shfl_xor(pr, off);
    if (j == 0) out[b] = pr + bfc;
}

extern "C" void kernel_launch(void* const* d_in, const int* in_sizes, int n_in,
                              void* d_out, int out_size, void* d_ws, size_t ws_size,
                              hipStream_t stream) {
    (void)d_ws; (void)ws_size; (void)n_in; (void)out_size;
    const float* x    = (const float*)d_in[0];
    const float* W_ih = (const float*)d_in[1];
    const float* W_hh = (const float*)d_in[2];
    const float* b_ih = (const float*)d_in[3];
    const float* b_hh = (const float*)d_in[4];
    const float* W_fc = (const float*)d_in[5];
    const float* b_fc = (const float*)d_in[6];
    float* out = (float*)d_out;

    const int B = in_sizes[0] / TSTEPS;   // 2048
    rnn_fused<<<dim3(B), dim3(64), 0, stream>>>(x, W_ih, W_hh, b_ih, b_hh,
                                                W_fc, b_fc, out);
}